// Round 4
// baseline (204.467 us; speedup 1.0000x reference)
//
#include <hip/hip_runtime.h>

// ---------------------------------------------------------------------------
// MalConv fused: GEMM M=16000, K=4000, N=256 (W1||W2) bf16 MFMA 16x16x32,
// epilogue GLU+relu+segmented-max in registers, then tiny FC.
//
// Round-4: R2 structure (coop A staging, ping-pong, 1 barrier/kt; B
// global->reg prefetched 1 ahead) but WG tile 128M x 64N -> grid 500,
// 2 WGs/CU, 4 waves/SIMD. Co-resident WGs have independent barriers so the
// vmcnt(0) barrier-drain of one overlaps the other's MFMA. All 8 waves of a
// WG load IDENTICAL B fragments (L1-served). Register GLU pairing (wave owns
// o and o+128) -> no epilogue exchange. acc = 4 frags = 16 VGPRs.
// ---------------------------------------------------------------------------

typedef __attribute__((ext_vector_type(8))) short short8;
typedef __attribute__((ext_vector_type(4))) float f32x4;

__device__ __forceinline__ unsigned short f2b(float f) {
    union { float f; unsigned u; } un;
    un.f = f;
    unsigned u = un.u;
    return (unsigned short)((u + 0x7FFFu + ((u >> 16) & 1u)) >> 16);  // RNE
}

#define KT_COUNT 125                              // K = 4000 = 125 * 32
#define WS_BBLK_BYTES (KT_COUNT * 256 * 32 * 2)   // 2,048,000 B bf16 weights
#define WS_MWS_OFF WS_BBLK_BYTES                  // 8*128 f32 max accumulator

// Pack W1,W2 (fp32 [128][8][500]) -> bf16 Bblk[kt][o][j]  (r=kt*32+j, k=r>>3,
// c=r&7). One uint4 per thread; coalesced writes. Also zeros m_ws.
__global__ __launch_bounds__(256) void prep_weights(
        const float* __restrict__ W1, const float* __restrict__ W2,
        unsigned short* __restrict__ Bblk, float* __restrict__ m_ws) {
    int u   = blockIdx.x * 256 + threadIdx.x;     // 0 .. 127,999 (uint4 idx)
    int kt  = u >> 10;
    int rem = u & 1023;
    int o   = rem >> 2;                           // 0..255
    int g   = rem & 3;
    int k   = kt * 4 + g;                         // 0..499
    const float* W = (o < 128) ? W1 : W2;
    int oo = o & 127;
    unsigned short v[8];
#pragma unroll
    for (int c = 0; c < 8; ++c) v[c] = f2b(W[oo * 4000 + c * 500 + k]);
    uint4 pack;
    pack.x = (unsigned)v[0] | ((unsigned)v[1] << 16);
    pack.y = (unsigned)v[2] | ((unsigned)v[3] << 16);
    pack.z = (unsigned)v[4] | ((unsigned)v[5] << 16);
    pack.w = (unsigned)v[6] | ((unsigned)v[7] << 16);
    *(uint4*)&Bblk[u * 8] = pack;
    if (blockIdx.x < 4) m_ws[blockIdx.x * 256 + threadIdx.x] = 0.f;
}

// 500 WGs x 512 threads; WG tile 128M x 64N (o-block of 32 paired with +128).
// Wave w = m-subtile (16 rows). Per kt: 1 A frag, 4 B frags, 4 MFMA.
__global__ __launch_bounds__(512, 4) void malconv_main(
        const int* __restrict__ x, const float* __restrict__ emb,
        const float* __restrict__ b1, const float* __restrict__ b2,
        const unsigned short* __restrict__ Bblk, float* __restrict__ m_ws) {
    __shared__ __align__(16) unsigned short embb[257 * 8];      // 4.1 KB
    __shared__ __align__(16) unsigned short Alds[2][128 * 40];  // ping-pong A

    const int t = threadIdx.x;
    for (int e = t; e < 257 * 8; e += 512) embb[e] = f2b(emb[e]);

    const int nb = blockIdx.x & 3;            // n-block: o in [nb*32, nb*32+32)
    const int m0 = (blockIdx.x >> 2) * 128;   // m-tile base (125 tiles)
    const int lane = t & 63, wave = t >> 6;
    const int quad = lane >> 4, l16 = lane & 15;

    // A staging: thread t handles (row ar = t>>2, k-pos aj = t&3)
    const int ar = t >> 2, aj = t & 3;
    const int* xptr = x + (m0 + ar) * 500 + aj;

    // B fragments (identical across all 8 waves -> L1 hits):
    // ni0: o=nb*32+l16, ni1: +16, ni2: +128 (W2), ni3: +144
    const unsigned short* bbase = Bblk + (nb * 32 + l16) * 32 + quad * 8;

    f32x4 acc[4];
#pragma unroll
    for (int ni = 0; ni < 4; ++ni) {
        f32x4 z = {0.f, 0.f, 0.f, 0.f};
        acc[ni] = z;
    }

    __syncthreads();  // embb ready

    // preamble: stage kt=0 into buf 0; prefetch x for kt=1; preload B(kt=0)
    {
        int xv = xptr[0];
        *(uint4*)&Alds[0][ar * 40 + aj * 8] = *(const uint4*)&embb[xv * 8];
    }
    int xvn = xptr[4];
    short8 bcur[4], bnxt[4];
    bcur[0] = *(const short8*)(bbase);
    bcur[1] = *(const short8*)(bbase + 512);
    bcur[2] = *(const short8*)(bbase + 4096);
    bcur[3] = *(const short8*)(bbase + 4608);
    __syncthreads();  // buf 0 ready

    for (int kt = 0; kt < KT_COUNT; ++kt) {
        const int cur = kt & 1;
        // prefetch next B tile (in flight across this iteration)
        if (kt < KT_COUNT - 1) {
            const unsigned short* bb = bbase + (kt + 1) * 8192;
            bnxt[0] = *(const short8*)(bb);
            bnxt[1] = *(const short8*)(bb + 512);
            bnxt[2] = *(const short8*)(bb + 4096);
            bnxt[3] = *(const short8*)(bb + 4608);
        }
        // A fragment from LDS (rows wave*16 + l16, r-block quad)
        short8 afrag = *(const short8*)
            &Alds[cur][(wave * 16 + l16) * 40 + quad * 8];
        // stage next A tile into the other buffer
        if (kt < KT_COUNT - 1) {
            *(uint4*)&Alds[cur ^ 1][ar * 40 + aj * 8] =
                *(const uint4*)&embb[xvn * 8];
            if (kt < KT_COUNT - 2) xvn = xptr[(kt + 2) * 4];
        }
        // MFMA: 4 frags (ni 0,1 = W1 cols; ni 2,3 = W2 cols, same o +128)
#pragma unroll
        for (int ni = 0; ni < 4; ++ni)
            acc[ni] = __builtin_amdgcn_mfma_f32_16x16x32_bf16(
                afrag, bcur[ni], acc[ni], 0, 0, 0);
#pragma unroll
        for (int ni = 0; ni < 4; ++ni) bcur[ni] = bnxt[ni];
        __syncthreads();
    }

    // ---- epilogue: register GLU + segmented max (no barrier needed) ----
    const int b0 = m0 / 2000;
    const int bsplit = (b0 + 1) * 2000;          // first patch of batch b0+1
    const bool crosses = (m0 + 127) >= bsplit && bsplit <= 16000 - 1;
#pragma unroll
    for (int ni = 0; ni < 2; ++ni) {
        int o = nb * 32 + ni * 16 + l16;
        float bb1 = b1[o], bb2 = b2[o];
        float mx0 = 0.f, mx1 = 0.f;              // h >= 0 always
#pragma unroll
        for (int r = 0; r < 4; ++r) {
            int ml = wave * 16 + quad * 4 + r;   // row within WG tile
            float g1 = acc[ni][r] + bb1;         // W1 frag
            float g2 = acc[ni + 2][r] + bb2;     // matching W2 frag
            float h = fmaxf(g1 / (1.f + __expf(-g2)), 0.f);
            if (m0 + ml >= bsplit) mx1 = fmaxf(mx1, h);
            else                   mx0 = fmaxf(mx0, h);
        }
        // reduce across the 4 quads (same o, different rows)
        mx0 = fmaxf(mx0, __shfl_xor(mx0, 16));
        mx0 = fmaxf(mx0, __shfl_xor(mx0, 32));
        mx1 = fmaxf(mx1, __shfl_xor(mx1, 16));
        mx1 = fmaxf(mx1, __shfl_xor(mx1, 32));
        if (quad == 0) {
            // nonneg floats: int compare == float compare
            atomicMax((int*)&m_ws[b0 * 128 + o], __float_as_int(mx0));
            if (crosses)
                atomicMax((int*)&m_ws[(b0 + 1) * 128 + o], __float_as_int(mx1));
        }
    }
}

// out[b][j] = sum_o m_ws[b][o] * fcW[j][o] + fcb[j]   (16 outputs)
__global__ void fc_kernel(const float* __restrict__ m_ws,
                          const float* __restrict__ fcW,
                          const float* __restrict__ fcb,
                          float* __restrict__ out) {
    int t = threadIdx.x;
    if (t < 16) {
        int b = t >> 1, j = t & 1;
        float s = 0.f;
        for (int o = 0; o < 128; ++o) s += m_ws[b * 128 + o] * fcW[j * 128 + o];
        out[t] = s + fcb[j];
    }
}

extern "C" void kernel_launch(void* const* d_in, const int* in_sizes, int n_in,
                              void* d_out, int out_size, void* d_ws, size_t ws_size,
                              hipStream_t stream) {
    const int*   x   = (const int*)d_in[0];     // [8, 1e6] values 0..256
    const float* emb = (const float*)d_in[1];   // [257, 8]
    const float* W1  = (const float*)d_in[2];   // [128, 8, 500]
    const float* b1  = (const float*)d_in[3];   // [128]
    const float* W2  = (const float*)d_in[4];   // [128, 8, 500]
    const float* b2  = (const float*)d_in[5];   // [128]
    const float* fcW = (const float*)d_in[6];   // [2, 128]
    const float* fcb = (const float*)d_in[7];   // [2]
    float* out = (float*)d_out;                 // [8, 2]

    unsigned short* Bblk = (unsigned short*)d_ws;
    float* m_ws = (float*)((char*)d_ws + WS_MWS_OFF);

    prep_weights<<<500, 256, 0, stream>>>(W1, W2, Bblk, m_ws);
    malconv_main<<<500, 512, 0, stream>>>(x, emb, b1, b2, Bblk, m_ws);
    fc_kernel<<<1, 64, 0, stream>>>(m_ws, fcW, fcb, out);
}

// Round 5
// 202.457 us; speedup vs baseline: 1.0099x; 1.0099x over previous
//
#include <hip/hip_runtime.h>

// ---------------------------------------------------------------------------
// MalConv fused: GEMM M=16000, K=4000, N=256 (W1||W2) bf16 MFMA 16x16x32,
// epilogue GLU+relu+segmented-max in registers, then tiny FC.
//
// Round-5: grid 250 (1 WG per 64-row m-tile -> x read exactly once), 1024
// threads = 16 waves = 4 waves/SIMD. A staged in 5-kt groups (ONE barrier
// per 5 kt, 25 total): 1280 slots (64 rows x 20 k-pos), every thread stages
// >=1 slot with near-coalesced x loads; x prefetched one group ahead.
// B global->reg rolling prefetch (4 waves per nq share -> L1). Register GLU
// pairing (wave owns o and o+128). prep_weights rewritten fully coalesced.
// ---------------------------------------------------------------------------

typedef __attribute__((ext_vector_type(8))) short short8;
typedef __attribute__((ext_vector_type(4))) float f32x4;

__device__ __forceinline__ unsigned short f2b(float f) {
    union { float f; unsigned u; } un;
    un.f = f;
    unsigned u = un.u;
    return (unsigned short)((u + 0x7FFFu + ((u >> 16) & 1u)) >> 16);  // RNE
}

#define KT_COUNT 125                              // K = 4000 = 125 * 32
#define NGROUPS 25                                // 5 kt per group
#define WS_BBLK_BYTES (KT_COUNT * 256 * 32 * 2)   // 2,048,000 B bf16 weights
#define WS_MWS_OFF WS_BBLK_BYTES                  // 8*128 f32 max accumulator

// Coalesced repack: W1,W2 (fp32 [128][8][500]) -> bf16 Bblk[kt][o][j]
// (j = kl*8 + c, k = kt*4 + kl). Block = one o (256 blocks); thread = one kt.
// Reads: 8 float4 loads, lanes consecutive kt -> fully coalesced.
__global__ __launch_bounds__(128) void prep_weights(
        const float* __restrict__ W1, const float* __restrict__ W2,
        unsigned short* __restrict__ Bblk, float* __restrict__ m_ws) {
    const int o  = blockIdx.x;                    // 0..255
    const int kt = threadIdx.x;                   // 0..127 (active < 125)
    if (kt < KT_COUNT) {
        const float* W = (o < 128) ? W1 : W2;
        const int oo = o & 127;
        unsigned short v[32];
#pragma unroll
        for (int c = 0; c < 8; ++c) {
            float4 f = *(const float4*)&W[oo * 4000 + c * 500 + kt * 4];
            v[c]      = f2b(f.x);
            v[8 + c]  = f2b(f.y);
            v[16 + c] = f2b(f.z);
            v[24 + c] = f2b(f.w);
        }
        unsigned short* dst = Bblk + kt * 8192 + o * 32;
#pragma unroll
        for (int q = 0; q < 4; ++q) {
            uint4 p;
            p.x = (unsigned)v[q * 8 + 0] | ((unsigned)v[q * 8 + 1] << 16);
            p.y = (unsigned)v[q * 8 + 2] | ((unsigned)v[q * 8 + 3] << 16);
            p.z = (unsigned)v[q * 8 + 4] | ((unsigned)v[q * 8 + 5] << 16);
            p.w = (unsigned)v[q * 8 + 6] | ((unsigned)v[q * 8 + 7] << 16);
            *(uint4*)(dst + q * 8) = p;
        }
    }
    if (blockIdx.x == 0)
        for (int i = threadIdx.x; i < 8 * 128; i += 128) m_ws[i] = 0.f;
}

// 250 WGs x 1024 threads; WG tile 64M x 256N (=128 o-pairs).
// Wave w: mq=w>>2 (rows [mq*16,mq*16+16)), nq=w&3 (32 o-pairs).
__global__ __launch_bounds__(1024, 4) void malconv_main(
        const int* __restrict__ x, const float* __restrict__ emb,
        const float* __restrict__ b1, const float* __restrict__ b2,
        const unsigned short* __restrict__ Bblk, float* __restrict__ m_ws) {
    __shared__ __align__(16) unsigned short embb[257 * 8];          // 4.1 KB
    __shared__ __align__(16) unsigned short Abuf[2 * 5 * 64 * 40];  // 51.2 KB

    const int t = threadIdx.x;
    for (int e = t; e < 257 * 8; e += 1024) embb[e] = f2b(emb[e]);

    const int m0 = blockIdx.x * 64;
    const int lane = t & 63, wave = t >> 6;
    const int quad = lane >> 4, l16 = lane & 15;
    const int mq   = wave >> 2, nq = wave & 3;

    // --- staging slots: slot s -> row r = s/20, k-pos p = s%20 within group;
    //     kt_local = p>>2, aj = p&3. Threads 0..1023 take slot t; threads
    //     768..1023 also take slot t+256 (covers 1280 slots). ---
    const int s0 = t;
    const int r0 = s0 / 20, p0 = s0 - r0 * 20;
    const bool two = (t >= 768);
    const int s1 = t + 256;
    const int r1 = s1 / 20, p1 = s1 - r1 * 20;
    const int* xrow0 = x + (m0 + r0) * 500 + p0;
    const int* xrow1 = x + (m0 + r1) * 500 + p1;
    const int aoff0 = (p0 >> 2) * 2560 + r0 * 40 + (p0 & 3) * 8;
    const int aoff1 = (p1 >> 2) * 2560 + r1 * 40 + (p1 & 3) * 8;

    // B fragment base (identical across mq -> L1): rows o = nq*32+l16 (+16,
    // +128, +144), 32 shorts/row, chunk quad*8; kt stride 8192 shorts.
    const unsigned short* bbase = Bblk + (nq * 32 + l16) * 32 + quad * 8;

    f32x4 acc[4];
#pragma unroll
    for (int ni = 0; ni < 4; ++ni) {
        f32x4 z = {0.f, 0.f, 0.f, 0.f};
        acc[ni] = z;
    }

    __syncthreads();  // embb ready

    // preamble: stage group 0 into buf 0, prefetch x for group 1, preload B
    {
        int xv0 = xrow0[0];
        int xv1 = two ? xrow1[0] : 0;
        *(uint4*)&Abuf[aoff0] = *(const uint4*)&embb[xv0 * 8];
        if (two) *(uint4*)&Abuf[aoff1] = *(const uint4*)&embb[xv1 * 8];
    }
    int xc0 = xrow0[20];
    int xc1 = two ? xrow1[20] : 0;
    short8 bcur[4], bnxt[4];
    bcur[0] = *(const short8*)(bbase);
    bcur[1] = *(const short8*)(bbase + 512);
    bcur[2] = *(const short8*)(bbase + 4096);
    bcur[3] = *(const short8*)(bbase + 4608);
    __syncthreads();  // buf 0 staged

    for (int g = 0; g < NGROUPS; ++g) {
        const int buf = (g & 1) * 12800;
        // x prefetch for group g+2 (issued now, consumed next group)
        const int gn = (g + 2 < NGROUPS) ? g + 2 : NGROUPS - 1;
        int xn0 = xrow0[gn * 20];
        int xn1 = two ? xrow1[gn * 20] : 0;
        // stage group g+1 into the other buffer using x loaded last group
        if (g < NGROUPS - 1) {
            const int ob = buf ^ 12800;
            *(uint4*)&Abuf[ob + aoff0] = *(const uint4*)&embb[xc0 * 8];
            if (two) *(uint4*)&Abuf[ob + aoff1] = *(const uint4*)&embb[xc1 * 8];
        }
        // compute 5 kt from current buffer, rolling B prefetch
#pragma unroll
        for (int ktl = 0; ktl < 5; ++ktl) {
            const int ktg = g * 5 + ktl;
            const int ktn = (ktg + 1 < KT_COUNT) ? ktg + 1 : KT_COUNT - 1;
            const unsigned short* bb = bbase + ktn * 8192;
            bnxt[0] = *(const short8*)(bb);
            bnxt[1] = *(const short8*)(bb + 512);
            bnxt[2] = *(const short8*)(bb + 4096);
            bnxt[3] = *(const short8*)(bb + 4608);
            short8 af = *(const short8*)
                &Abuf[buf + ktl * 2560 + (mq * 16 + l16) * 40 + quad * 8];
#pragma unroll
            for (int ni = 0; ni < 4; ++ni)
                acc[ni] = __builtin_amdgcn_mfma_f32_16x16x32_bf16(
                    af, bcur[ni], acc[ni], 0, 0, 0);
#pragma unroll
            for (int ni = 0; ni < 4; ++ni) bcur[ni] = bnxt[ni];
        }
        xc0 = xn0; xc1 = xn1;
        __syncthreads();
    }

    // ---- epilogue: register GLU + segmented max (no barrier needed) ----
    const int b0 = m0 / 2000;
    const int bsplit = (b0 + 1) * 2000;          // first patch of batch b0+1
    const bool crosses = (m0 + 63) >= bsplit && (b0 + 1) < 8;
#pragma unroll
    for (int ni = 0; ni < 2; ++ni) {
        int o = nq * 32 + ni * 16 + l16;
        float bb1 = b1[o], bb2 = b2[o];
        float mx0 = 0.f, mx1 = 0.f;              // h >= 0 always
#pragma unroll
        for (int r = 0; r < 4; ++r) {
            int ml = mq * 16 + quad * 4 + r;     // row within 64-row tile
            float g1 = acc[ni][r] + bb1;         // W1 frag
            float g2 = acc[ni + 2][r] + bb2;     // matching W2 frag
            float h = fmaxf(g1 / (1.f + __expf(-g2)), 0.f);
            if (m0 + ml >= bsplit) mx1 = fmaxf(mx1, h);
            else                   mx0 = fmaxf(mx0, h);
        }
        // reduce across the 4 quads (same o, different rows)
        mx0 = fmaxf(mx0, __shfl_xor(mx0, 16));
        mx0 = fmaxf(mx0, __shfl_xor(mx0, 32));
        mx1 = fmaxf(mx1, __shfl_xor(mx1, 16));
        mx1 = fmaxf(mx1, __shfl_xor(mx1, 32));
        if (quad == 0) {
            // nonneg floats: int compare == float compare
            atomicMax((int*)&m_ws[b0 * 128 + o], __float_as_int(mx0));
            if (crosses)
                atomicMax((int*)&m_ws[(b0 + 1) * 128 + o], __float_as_int(mx1));
        }
    }
}

// out[b][j] = sum_o m_ws[b][o] * fcW[j][o] + fcb[j]   (16 outputs)
__global__ void fc_kernel(const float* __restrict__ m_ws,
                          const float* __restrict__ fcW,
                          const float* __restrict__ fcb,
                          float* __restrict__ out) {
    int t = threadIdx.x;
    if (t < 16) {
        int b = t >> 1, j = t & 1;
        float s = 0.f;
        for (int o = 0; o < 128; ++o) s += m_ws[b * 128 + o] * fcW[j * 128 + o];
        out[t] = s + fcb[j];
    }
}

extern "C" void kernel_launch(void* const* d_in, const int* in_sizes, int n_in,
                              void* d_out, int out_size, void* d_ws, size_t ws_size,
                              hipStream_t stream) {
    const int*   x   = (const int*)d_in[0];     // [8, 1e6] values 0..256
    const float* emb = (const float*)d_in[1];   // [257, 8]
    const float* W1  = (const float*)d_in[2];   // [128, 8, 500]
    const float* b1  = (const float*)d_in[3];   // [128]
    const float* W2  = (const float*)d_in[4];   // [128, 8, 500]
    const float* b2  = (const float*)d_in[5];   // [128]
    const float* fcW = (const float*)d_in[6];   // [2, 128]
    const float* fcb = (const float*)d_in[7];   // [2]
    float* out = (float*)d_out;                 // [8, 2]

    unsigned short* Bblk = (unsigned short*)d_ws;
    float* m_ws = (float*)((char*)d_ws + WS_MWS_OFF);

    prep_weights<<<256, 128, 0, stream>>>(W1, W2, Bblk, m_ws);
    malconv_main<<<250, 1024, 0, stream>>>(x, emb, b1, b2, Bblk, m_ws);
    fc_kernel<<<1, 64, 0, stream>>>(m_ws, fcW, fcb, out);
}

// Round 6
// 151.432 us; speedup vs baseline: 1.3502x; 1.3369x over previous
//
#include <hip/hip_runtime.h>

// ---------------------------------------------------------------------------
// MalConv fused: GEMM M=16000, K=4000, N=256 (W1||W2) bf16 MFMA 16x16x32,
// epilogue GLU+relu+segmented-max in registers, then tiny FC.
//
// Round-6 = Round-2 structure (best measured: grid 250, 512 thr, coop A
// staging, ping-pong A, ONE barrier/kt, B global->reg depth-1) with ONE key
// change: x for the whole 64-row tile is staged into LDS as u16 (62.5 KB) in
// a coalesced prologue, so the per-kt barrier's forced vmcnt(0) never drains
// an HBM-latency x load -- only L2-resident B loads issued at the top of the
// same iteration. Plus R3's register GLU pairing (wave owns o and o+128):
// no epilogue LDS exchange. LDS total ~78 KB (160 KB available).
// ---------------------------------------------------------------------------

typedef __attribute__((ext_vector_type(8))) short short8;
typedef __attribute__((ext_vector_type(4))) float f32x4;

__device__ __forceinline__ unsigned short f2b(float f) {
    union { float f; unsigned u; } un;
    un.f = f;
    unsigned u = un.u;
    return (unsigned short)((u + 0x7FFFu + ((u >> 16) & 1u)) >> 16);  // RNE
}

#define KT_COUNT 125                              // K = 4000 = 125 * 32
#define WS_BBLK_BYTES (KT_COUNT * 256 * 32 * 2)   // 2,048,000 B bf16 weights
#define WS_MWS_OFF WS_BBLK_BYTES                  // 8*128 f32 max accumulator

// Coalesced repack: W1,W2 (fp32 [128][8][500]) -> bf16 Bblk[kt][o][j]
// (j = kl*8 + c, k = kt*4 + kl). Block = one o; thread = one kt. Also zeros
// m_ws.
__global__ __launch_bounds__(128) void prep_weights(
        const float* __restrict__ W1, const float* __restrict__ W2,
        unsigned short* __restrict__ Bblk, float* __restrict__ m_ws) {
    const int o  = blockIdx.x;                    // 0..255
    const int kt = threadIdx.x;                   // 0..127 (active < 125)
    if (kt < KT_COUNT) {
        const float* W = (o < 128) ? W1 : W2;
        const int oo = o & 127;
        unsigned short v[32];
#pragma unroll
        for (int c = 0; c < 8; ++c) {
            float4 f = *(const float4*)&W[oo * 4000 + c * 500 + kt * 4];
            v[c]      = f2b(f.x);
            v[8 + c]  = f2b(f.y);
            v[16 + c] = f2b(f.z);
            v[24 + c] = f2b(f.w);
        }
        unsigned short* dst = Bblk + kt * 8192 + o * 32;
#pragma unroll
        for (int q = 0; q < 4; ++q) {
            uint4 p;
            p.x = (unsigned)v[q * 8 + 0] | ((unsigned)v[q * 8 + 1] << 16);
            p.y = (unsigned)v[q * 8 + 2] | ((unsigned)v[q * 8 + 3] << 16);
            p.z = (unsigned)v[q * 8 + 4] | ((unsigned)v[q * 8 + 5] << 16);
            p.w = (unsigned)v[q * 8 + 6] | ((unsigned)v[q * 8 + 7] << 16);
            *(uint4*)(dst + q * 8) = p;
        }
    }
    if (blockIdx.x == 0)
        for (int i = threadIdx.x; i < 8 * 128; i += 128) m_ws[i] = 0.f;
}

// 250 WGs x 512 threads; WG tile 64M x 256N (=128 o-pairs).
// Wave w: mq=w>>2 (rows [mq*32, mq*32+32)), nq=w&3 (32 o-pairs).
// acc[2][4]: mi = m 16-block; ni 0,1 = W1 cols, ni 2,3 = matching W2 cols.
__global__ __launch_bounds__(512, 2) void malconv_main(
        const int* __restrict__ x, const float* __restrict__ emb,
        const float* __restrict__ b1, const float* __restrict__ b2,
        const unsigned short* __restrict__ Bblk, float* __restrict__ m_ws) {
    __shared__ __align__(16) unsigned short embb[257 * 8];     // 4.1 KB
    __shared__ __align__(16) unsigned short Alds[2][64 * 40];  // 10.2 KB
    __shared__ __align__(16) unsigned short xlds[64 * 500];    // 62.5 KB u16

    const int t = threadIdx.x;
    const int m0 = blockIdx.x * 64;

    // ---- prologue: emb -> LDS (bf16) and x-tile -> LDS (u16), coalesced ----
    for (int e = t; e < 257 * 8; e += 512) embb[e] = f2b(emb[e]);
    {
        const int4* xg = (const int4*)(x + m0 * 500);   // 8000 int4s
        for (int i = t; i < 8000; i += 512) {
            int4 v = xg[i];
            ushort4 s;
            s.x = (unsigned short)v.x; s.y = (unsigned short)v.y;
            s.z = (unsigned short)v.z; s.w = (unsigned short)v.w;
            *(ushort4*)&xlds[i * 4] = s;
        }
    }

    const int lane = t & 63, wave = t >> 6;
    const int quad = lane >> 4, l16 = lane & 15;
    const int mq   = wave >> 2, nq = wave & 3;

    // A staging (threads 0..255 = waves 0..3): row ar (0..63), k-pos aj (0..3)
    const int ar = t >> 2, aj = t & 3;

    // B fragments: ni0: o=nq*32+l16, ni1: +16, ni2: +128 (W2), ni3: +144.
    const unsigned short* bbase = Bblk + (nq * 32 + l16) * 32 + quad * 8;

    f32x4 acc[2][4];
#pragma unroll
    for (int mi = 0; mi < 2; ++mi)
#pragma unroll
        for (int ni = 0; ni < 4; ++ni) {
            f32x4 z = {0.f, 0.f, 0.f, 0.f};
            acc[mi][ni] = z;
        }

    __syncthreads();  // embb + xlds ready

    // preamble: stage kt=0 into buf 0; prefetch x (from LDS) for kt=1;
    // preload B(kt=0)
    unsigned short xvn = 0;
    if (t < 256) {
        unsigned short xv = xlds[ar * 500 + aj];
        *(uint4*)&Alds[0][ar * 40 + aj * 8] = *(const uint4*)&embb[xv * 8];
        xvn = xlds[ar * 500 + 4 + aj];
    }
    short8 bcur[4], bnxt[4];
    bcur[0] = *(const short8*)(bbase);
    bcur[1] = *(const short8*)(bbase + 512);
    bcur[2] = *(const short8*)(bbase + 4096);
    bcur[3] = *(const short8*)(bbase + 4608);
    __syncthreads();  // buf 0 staged

    for (int kt = 0; kt < KT_COUNT; ++kt) {
        const int cur = kt & 1;
        // B prefetch for kt+1, issued FIRST (max time before barrier drain)
        if (kt < KT_COUNT - 1) {
            const unsigned short* bb = bbase + (kt + 1) * 8192;
            bnxt[0] = *(const short8*)(bb);
            bnxt[1] = *(const short8*)(bb + 512);
            bnxt[2] = *(const short8*)(bb + 4096);
            bnxt[3] = *(const short8*)(bb + 4608);
        }
        // A fragments from LDS
        short8 afrag[2];
#pragma unroll
        for (int mi = 0; mi < 2; ++mi)
            afrag[mi] = *(const short8*)
                &Alds[cur][(mq * 32 + mi * 16 + l16) * 40 + quad * 8];
        // stage kt+1 into the other buffer; x value came from LDS 2 kt ago
        if (t < 256 && kt < KT_COUNT - 1) {
            *(uint4*)&Alds[cur ^ 1][ar * 40 + aj * 8] =
                *(const uint4*)&embb[xvn * 8];
            if (kt < KT_COUNT - 2) xvn = xlds[ar * 500 + (kt + 2) * 4 + aj];
        }
        // MFMA: 8 per wave per kt
#pragma unroll
        for (int mi = 0; mi < 2; ++mi)
#pragma unroll
            for (int ni = 0; ni < 4; ++ni)
                acc[mi][ni] = __builtin_amdgcn_mfma_f32_16x16x32_bf16(
                    afrag[mi], bcur[ni], acc[mi][ni], 0, 0, 0);
#pragma unroll
        for (int ni = 0; ni < 4; ++ni) bcur[ni] = bnxt[ni];
        __syncthreads();
    }

    // ---- epilogue: register GLU + segmented max (no barrier needed) ----
    const int b0 = m0 / 2000;
    const int bsplit = (b0 + 1) * 2000;          // first patch of batch b0+1
    const bool crosses = (m0 + 63) >= bsplit;    // never OOB: last tile ends 15999
#pragma unroll
    for (int ni = 0; ni < 2; ++ni) {
        int o = nq * 32 + ni * 16 + l16;
        float bb1 = b1[o], bb2 = b2[o];
        float mx0 = 0.f, mx1 = 0.f;              // h >= 0 always
#pragma unroll
        for (int mi = 0; mi < 2; ++mi)
#pragma unroll
            for (int r = 0; r < 4; ++r) {
                int ml = mq * 32 + mi * 16 + quad * 4 + r;
                float g1 = acc[mi][ni][r] + bb1;       // W1 frag
                float g2 = acc[mi][ni + 2][r] + bb2;   // matching W2 frag
                float h = fmaxf(g1 / (1.f + __expf(-g2)), 0.f);
                if (m0 + ml >= bsplit) mx1 = fmaxf(mx1, h);
                else                   mx0 = fmaxf(mx0, h);
            }
        // reduce across the 4 quads (same o, different rows)
        mx0 = fmaxf(mx0, __shfl_xor(mx0, 16));
        mx0 = fmaxf(mx0, __shfl_xor(mx0, 32));
        mx1 = fmaxf(mx1, __shfl_xor(mx1, 16));
        mx1 = fmaxf(mx1, __shfl_xor(mx1, 32));
        if (quad == 0) {
            // nonneg floats: int compare == float compare
            atomicMax((int*)&m_ws[b0 * 128 + o], __float_as_int(mx0));
            if (crosses)
                atomicMax((int*)&m_ws[(b0 + 1) * 128 + o], __float_as_int(mx1));
        }
    }
}

// out[b][j] = sum_o m_ws[b][o] * fcW[j][o] + fcb[j]   (16 outputs)
__global__ void fc_kernel(const float* __restrict__ m_ws,
                          const float* __restrict__ fcW,
                          const float* __restrict__ fcb,
                          float* __restrict__ out) {
    int t = threadIdx.x;
    if (t < 16) {
        int b = t >> 1, j = t & 1;
        float s = 0.f;
        for (int o = 0; o < 128; ++o) s += m_ws[b * 128 + o] * fcW[j * 128 + o];
        out[t] = s + fcb[j];
    }
}

extern "C" void kernel_launch(void* const* d_in, const int* in_sizes, int n_in,
                              void* d_out, int out_size, void* d_ws, size_t ws_size,
                              hipStream_t stream) {
    const int*   x   = (const int*)d_in[0];     // [8, 1e6] values 0..256
    const float* emb = (const float*)d_in[1];   // [257, 8]
    const float* W1  = (const float*)d_in[2];   // [128, 8, 500]
    const float* b1  = (const float*)d_in[3];   // [128]
    const float* W2  = (const float*)d_in[4];   // [128, 8, 500]
    const float* b2  = (const float*)d_in[5];   // [128]
    const float* fcW = (const float*)d_in[6];   // [2, 128]
    const float* fcb = (const float*)d_in[7];   // [2]
    float* out = (float*)d_out;                 // [8, 2]

    unsigned short* Bblk = (unsigned short*)d_ws;
    float* m_ws = (float*)((char*)d_ws + WS_MWS_OFF);

    prep_weights<<<256, 128, 0, stream>>>(W1, W2, Bblk, m_ws);
    malconv_main<<<250, 512, 0, stream>>>(x, emb, b1, b2, Bblk, m_ws);
    fc_kernel<<<1, 64, 0, stream>>>(m_ws, fcW, fcb, out);
}